// Round 10
// baseline (131.428 us; speedup 1.0000x reference)
//
#include <hip/hip_runtime.h>
#include <hip/hip_fp16.h>
#include <math.h>

#define EPS 0.05f
#define INV_EPS 20.0f
#define BIGF 1e30f

typedef short bf16x8 __attribute__((ext_vector_type(8)));
typedef float f32x4 __attribute__((ext_vector_type(4)));

// HW packed f32->bf16 (RNE), lo16 = bf16(a), hi16 = bf16(b)
__device__ __forceinline__ unsigned cvtpk(float a, float b) {
  unsigned r;
  asm("v_cvt_pk_bf16_f32 %0, %1, %2" : "=v"(r) : "v"(a), "v"(b));
  return r;
}

struct Q4 { float4 a, b, c, d; };
__device__ __forceinline__ void loadQ(Q4& q, const float* p) {
  q.a = *(const float4*)p;       q.b = *(const float4*)(p + 4);
  q.c = *(const float4*)(p + 8); q.d = *(const float4*)(p + 12);
}
// pack 16 f32 -> bf16 (HW cvt_pk), store 32B to LDS, accumulate bf16-rounded |x|^2
__device__ __forceinline__ void packQ(short* dst, const Q4& q, float& sq) {
  uint4 w0, w1;
  w0.x = cvtpk(q.a.x, q.a.y); w0.y = cvtpk(q.a.z, q.a.w);
  w0.z = cvtpk(q.b.x, q.b.y); w0.w = cvtpk(q.b.z, q.b.w);
  w1.x = cvtpk(q.c.x, q.c.y); w1.y = cvtpk(q.c.z, q.c.w);
  w1.z = cvtpk(q.d.x, q.d.y); w1.w = cvtpk(q.d.z, q.d.w);
  unsigned ws[8] = {w0.x, w0.y, w0.z, w0.w, w1.x, w1.y, w1.z, w1.w};
  #pragma unroll
  for (int k = 0; k < 8; k++) {
    float lo = __uint_as_float(ws[k] << 16);
    float hi = __uint_as_float(ws[k] & 0xffff0000u);
    sq += lo * lo + hi * hi;
  }
  *(uint4*)dst = w0;
  *(uint4*)(dst + 8) = w1;
}

// ---- LDS arena (bytes), phase-lifetime aliased:
#define S_HSA   0        // short[128][72] = 18432
#define S_HSB   18432    //               -> 36864
#define S_KR    36864    // float[48][116] = 22272 -> 59136
#define S_DIAG  59136    // f32[128]  -> 59648 (per H-row bf16 |h|^2)
#define S_DSL   59648    // f32[160]  -> 60288 (compact diag; later dual terms)
#define S_IA    60288    // int[48]   -> 60480
#define S_IB    60480    // int[112]  -> 60928
#define S_RV    60928    // f32[48]   -> 61120
#define S_CV    61120    // f32[112]  -> 61568
#define S_CNT   61568    // int[4]    -> 61584
#define S_UV    61584    // f32[48]   -> 61776
#define S_VV    61776    // f32[112]  -> 62224
#define S_FLG   62224    // int[12]: [0..2]=fU (waves 0-2), [4..10]=fV (waves 0-6)
#define SMEM_SZ 62272

// single-batch LayerNorm + classifier, one wave (64 lanes)
__device__ __forceinline__ void finish_batch(int b, int lane,
    const float* __restrict__ fusedv, const float* __restrict__ dxv,
    const float* __restrict__ lnw, const float* __restrict__ lnb,
    const float* __restrict__ Wcls, const float* __restrict__ bcls,
    float* __restrict__ out)
{
  float f320 = __hip_atomic_load(dxv + b, __ATOMIC_RELAXED, __HIP_MEMORY_SCOPE_AGENT);
  float fv[5];
  #pragma unroll
  for (int c = 0; c < 5; c++)
    fv[c] = __hip_atomic_load(fusedv + b * 320 + c * 64 + lane,
                              __ATOMIC_RELAXED, __HIP_MEMORY_SCOPE_AGENT);
  float s = ((fv[0] + fv[1]) + (fv[2] + fv[3])) + fv[4];
  if (lane == 0) s += f320;
  #pragma unroll
  for (int d = 1; d < 64; d <<= 1) s += __shfl_xor(s, d);
  const float mu = s * (1.0f / 321.0f);
  float v = 0.f;
  #pragma unroll
  for (int c = 0; c < 5; c++) { float dd = fv[c] - mu; v += dd * dd; }
  if (lane == 0) { float dd = f320 - mu; v += dd * dd; }
  #pragma unroll
  for (int d = 1; d < 64; d <<= 1) v += __shfl_xor(v, d);
  const float rstd = rsqrtf(v * (1.0f / 321.0f) + 1e-5f);
  float p0 = 0.f, p1 = 0.f;
  #pragma unroll
  for (int c = 0; c < 5; c++) {
    int i = c * 64 + lane;
    float h = (fv[c] - mu) * rstd * lnw[i] + lnb[i];
    p0 += h * Wcls[i];
    p1 += h * Wcls[321 + i];
  }
  if (lane == 0) {
    float h = (f320 - mu) * rstd * lnw[320] + lnb[320];
    p0 += h * Wcls[320];
    p1 += h * Wcls[641];
  }
  #pragma unroll
  for (int d = 1; d < 64; d <<= 1) { p0 += __shfl_xor(p0, d); p1 += __shfl_xor(p1, d); }
  if (lane == 0) {
    out[b * 2]     = p0 + bcls[0];
    out[b * 2 + 1] = p1 + bcls[1];
  }
}

__global__ __launch_bounds__(512)
void k_mega(const float* __restrict__ H, const int* __restrict__ ttid,
            const int* __restrict__ amask,
            const float* __restrict__ Wc, const float* __restrict__ bc,
            const float* __restrict__ Ws, const float* __restrict__ bs,
            const float* __restrict__ gate,
            const float* __restrict__ lnw, const float* __restrict__ lnb,
            const float* __restrict__ Wcls, const float* __restrict__ bcls,
            float* __restrict__ dcross, float* __restrict__ fused,
            unsigned* __restrict__ ticket, float* __restrict__ out)
{
  __shared__ __align__(16) char smem[SMEM_SZ];
  const int t = threadIdx.x;
  const int bid = blockIdx.x;

  if (bid < 64) {
    // ================= compact-support Sinkhorn =================
    const int b = bid;
    short*  HsA  = (short*)(smem + S_HSA);
    short*  HsB  = (short*)(smem + S_HSB);
    float*  Kr   = (float*)(smem + S_KR);
    float*  diag = (float*)(smem + S_DIAG);
    float*  dslot= (float*)(smem + S_DSL);
    int*    ia   = (int*)(smem + S_IA);
    int*    ib   = (int*)(smem + S_IB);
    float*  rv   = (float*)(smem + S_RV);
    float*  cv   = (float*)(smem + S_CV);
    int*    cnts = (int*)(smem + S_CNT);
    float*  uv   = (float*)(smem + S_UV);
    float*  vv   = (float*)(smem + S_VV);
    volatile int* fU = (volatile int*)(smem + S_FLG);      // [0..2]
    volatile int* fV = (volatile int*)(smem + S_FLG) + 4;  // [0..6]

    const int lane = t & 63;
    const int w = t >> 6;

    // ---- issue 4 H chunks FIRST (independent of masks; 4-deep pipeline) ----
    const float* Hb = H + (size_t)b * (128 * 768);
    const int srow = t >> 2, sc0 = (t & 3) * 16;
    const float* srcB = Hb + srow * 768 + sc0;
    Q4 q0, q1, q2, q3;
    loadQ(q0, srcB);
    loadQ(q1, srcB + 64);
    loadQ(q2, srcB + 128);
    loadQ(q3, srcB + 192);

    // ---- Phase A: compact index lists via ballot prefix-sum ----
    int flagA = 0, flagB = 0;
    unsigned long long mA = 0, mB = 0;
    if (t < 128) {
      int a_ = amask[b*128 + t], tt_ = ttid[b*128 + t];
      flagA = (a_ == 1 && tt_ == 0);
      flagB = (a_ == 1 && tt_ == 1);
      mA = __ballot(flagA);
      mB = __ballot(flagB);
      if (lane == 0) { cnts[w] = __popcll(mA); cnts[2 + w] = __popcll(mB); }
    }
    for (int e = t; e < 48 * 116; e += 512) Kr[e] = BIGF;   // prefill
    if (t < 12) ((int*)(smem + S_FLG))[t] = 0;              // Phase-D flags
    __syncthreads();
    const int n0 = cnts[0] + cnts[1];   // <= 47
    const int n1 = cnts[2] + cnts[3];   // <= 112
    if (t < 128) {
      int offA = (w == 1) ? cnts[0] : 0;
      int offB = (w == 1) ? cnts[2] : 0;
      unsigned long long below = (1ull << lane) - 1ull;
      if (flagA) ia[offA + __popcll(mA & below)] = t;
      if (flagB) ib[offB + __popcll(mB & below)] = t;
    }
    float sq = 0.f;
    packQ(HsA + srow * 72 + sc0, q0, sq);   // chunk 0 -> HsA
    __syncthreads();    // ia/ib + HsA chunk0 visible

    // ---- Phase B: linear staging of all 128 rows; compact MFMA via
    //      per-lane fragment row indices read once through ia/ib ----
    const int wv = t >> 6;
    const int fm = lane & 15, fg = lane >> 4;
    int ar0 = 0, ar1 = 0, ar2 = 0, br = 0;
    if (wv < 7) {
      ar0 = (fm      < n0) ? ia[fm]      : 0;
      ar1 = (16 + fm < n0) ? ia[16 + fm] : 0;
      ar2 = (32 + fm < n0) ? ia[32 + fm] : 0;
      br  = (wv * 16 + fm < n1) ? ib[wv * 16 + fm] : 0;
    }

    f32x4 acc[3];
    #pragma unroll
    for (int r = 0; r < 3; r++) { acc[r][0]=0.f; acc[r][1]=0.f; acc[r][2]=0.f; acc[r][3]=0.f; }

    #pragma unroll
    for (int kc = 0; kc < 12; kc++) {
      if (kc) __syncthreads();   // chunk kc visible in cur; prior reads of nxt done
      short* cur = (kc & 1) ? HsB : HsA;
      short* nxt = (kc & 1) ? HsA : HsB;
      if (kc < 8) {              // prefetch chunk kc+4 into the just-freed slot
        const float* s2 = srcB + (kc + 4) * 64;
        if ((kc & 3) == 0)      loadQ(q0, s2);
        else if ((kc & 3) == 1) loadQ(q1, s2);
        else if ((kc & 3) == 2) loadQ(q2, s2);
        else                    loadQ(q3, s2);
      }
      if (kc < 11) {             // pack+store chunk kc+1 into the other buffer
        short* d = nxt + srow * 72 + sc0;
        const int m = (kc + 1) & 3;
        if (m == 0)      packQ(d, q0, sq);
        else if (m == 1) packQ(d, q1, sq);
        else if (m == 2) packQ(d, q2, sq);
        else             packQ(d, q3, sq);
      }
      if (wv < 7) {              // 3 row-tiles x col-tile wv, 21 tiles total
        #pragma unroll
        for (int ks = 0; ks < 2; ks++) {
          bf16x8 bfr = *(const bf16x8*)(cur + br * 72 + ks * 32 + fg * 8);
          bf16x8 a0f = *(const bf16x8*)(cur + ar0 * 72 + ks * 32 + fg * 8);
          acc[0] = __builtin_amdgcn_mfma_f32_16x16x32_bf16(a0f, bfr, acc[0], 0, 0, 0);
          bf16x8 a1f = *(const bf16x8*)(cur + ar1 * 72 + ks * 32 + fg * 8);
          acc[1] = __builtin_amdgcn_mfma_f32_16x16x32_bf16(a1f, bfr, acc[1], 0, 0, 0);
          bf16x8 a2f = *(const bf16x8*)(cur + ar2 * 72 + ks * 32 + fg * 8);
          acc[2] = __builtin_amdgcn_mfma_f32_16x16x32_bf16(a2f, bfr, acc[2], 0, 0, 0);
        }
      }
    }
    // per-row bf16 square-sum -> diag
    {
      float s = sq;
      s += __shfl_xor(s, 1); s += __shfl_xor(s, 2);
      if ((t & 3) == 0) diag[srow] = s;
    }
    __syncthreads();
    if (t < 160)   // compact diag gather
      dslot[t] = diag[(t < 48) ? ((t < n0) ? ia[t] : 0)
                               : ((t - 48 < n1) ? ib[t - 48] : 0)];
    __syncthreads();

    // ---- epilogue: Ce = sqrt(dA+dB-2G)*INV_EPS straight from f32 acc ----
    if (wv < 7) {
      int j = wv * 16 + fm;
      if (j < n1) {
        float dj = dslot[48 + j];
        #pragma unroll
        for (int r = 0; r < 3; r++) {
          #pragma unroll
          for (int q = 0; q < 4; q++) {
            int i = r * 16 + fg * 4 + q;
            if (i < n0) {
              float d2 = fmaxf(dslot[i] + dj - 2.0f * acc[r][q], 1e-6f);
              Kr[i * 116 + j] = sqrtf(d2) * INV_EPS;
            }
          }
        }
      }
    }
    __syncthreads();

    // ---- Phase C: shifts r/c, K transform in place ----
    if (t < 192) {  // r_i = min_j Ce
      int r = t >> 2, c = t & 3;
      const float* row = Kr + r * 116 + c * 28;
      float mn = BIGF;
      #pragma unroll
      for (int g = 0; g < 7; g++) {
        float4 x = *(const float4*)(row + g * 4);
        mn = fminf(mn, fminf(fminf(x.x, x.y), fminf(x.z, x.w)));
      }
      mn = fminf(mn, __shfl_xor(mn, 1));
      mn = fminf(mn, __shfl_xor(mn, 2));
      if (c == 0) rv[r] = mn;
    }
    __syncthreads();
    if (t < 448) {  // c_j = min_{i<n0} (Ce - r_i)
      int cl = t >> 2, rr = t & 3;
      float mn = BIGF;
      #pragma unroll
      for (int g = 0; g < 12; g++) {
        int i = rr * 12 + g;
        float v = (i < n0) ? (Kr[i * 116 + cl] - rv[i]) : BIGF;
        mn = fminf(mn, v);
      }
      mn = fminf(mn, __shfl_xor(mn, 1));
      mn = fminf(mn, __shfl_xor(mn, 2));
      if (rr == 0) cv[cl] = mn;
    }
    __syncthreads();
    for (int i = t >> 7; i < 48; i += 4) {  // K = exp(min(r+c-Ce,0))
      float ri = rv[i];
      for (int j = t & 127; j < 112; j += 128) {
        float ce = Kr[i * 116 + j];
        Kr[i * 116 + j] = __expf(fminf(ri + cv[j] - ce, 0.f));
      }
    }
    const float inv_n0 = 1.0f / (float)n0;
    const float inv_n1 = 1.0f / (float)n1;
    if (t < 112) vv[t] = (t < n1) ? inv_n1 * __expf(-cv[t]) : 0.f;  // v init
    __syncthreads();

    // ---- Phase D: 8-wave cooperative iterations, LDS flag sync (no barriers) --
    // u-step: waves 0-2 (t<192) -> (row g4 = t>>2, slice q4 = t&3), 28-elem slices
    // v-step: waves 0-6 (t<448) -> (col g4, slice q4), 12-elem column slices
    const int g4 = t >> 2, q4 = t & 3;
    const bool uRole = (t < 192);
    const bool vRole = (t < 448);

    float ku[28];
    if (uRole) {
      const float* kp = Kr + g4 * 116 + 28 * q4;
      #pragma unroll
      for (int i = 0; i < 7; i++) {
        float4 x = *(const float4*)(kp + 4 * i);
        ku[4*i] = x.x; ku[4*i+1] = x.y; ku[4*i+2] = x.z; ku[4*i+3] = x.w;
      }
    }
    float kv[12];
    if (vRole) {
      #pragma unroll
      for (int i = 0; i < 12; i++) kv[i] = Kr[(12 * q4 + i) * 116 + g4];
    }
    const float a_r = (uRole && g4 < n0) ? inv_n0 : 0.f;
    const float b_j = (vRole && g4 < n1) ? inv_n1 : 0.f;
    float Sfin = 1.f, Tfin = 1.f;

    for (int it = 0; it < 30; it++) {
      if (uRole) {                       // S_r = sum_j K[r][j] v_j
        if (it > 0) {                    // wait: v-step(it-1) done (reads+writes)
          for (;;) {
            int f0=fV[0],f1=fV[1],f2=fV[2],f3=fV[3],f4=fV[4],f5=fV[5],f6=fV[6];
            if (f0>=it&&f1>=it&&f2>=it&&f3>=it&&f4>=it&&f5>=it&&f6>=it) break;
          }
        }
        const float* vp = vv + 28 * q4;
        float a0 = 0.f, a1 = 0.f, a2 = 0.f, a3 = 0.f;
        #pragma unroll
        for (int i = 0; i < 7; i++) {
          float4 v4 = *(const float4*)(vp + 4 * i);
          a0 += ku[4*i]   * v4.x; a1 += ku[4*i+1] * v4.y;
          a2 += ku[4*i+2] * v4.z; a3 += ku[4*i+3] * v4.w;
        }
        float s = (a0 + a1) + (a2 + a3);
        s += __shfl_xor(s, 1);
        s += __shfl_xor(s, 2);
        Sfin = s;
        if (q4 == 0) uv[g4] = a_r * __builtin_amdgcn_rcpf(s);
        __asm__ volatile("s_waitcnt lgkmcnt(0)" ::: "memory");
        if (lane == 0) fU[w] = it + 1;   // wave w in {0,1,2}
      }
      if (vRole) {                       // T_j = sum_i K[i][j] u_i
        for (;;) {                       // wait: u-step(it) done
          int f0 = fU[0], f1 = fU[1], f2 = fU[2];
          if (f0 > it && f1 > it && f2 > it) break;
        }
        const float* up = uv + 12 * q4;
        float4 u0 = *(const float4*)(up);
        float4 u1 = *(const float4*)(up + 4);
        float4 u2 = *(const float4*)(up + 8);
        float p0 = kv[0]*u0.x + kv[1]*u0.y + kv[2]*u0.z + kv[3]*u0.w;
        float p1 = kv[4]*u1.x + kv[5]*u1.y + kv[6]*u1.z + kv[7]*u1.w;
        float p2 = kv[8]*u2.x + kv[9]*u2.y + kv[10]*u2.z + kv[11]*u2.w;
        float tsum = p0 + p1 + p2;
        tsum += __shfl_xor(tsum, 1);
        tsum += __shfl_xor(tsum, 2);
        Tfin = tsum;
        if (q4 == 0) vv[g4] = b_j * __builtin_amdgcn_rcpf(tsum);
        __asm__ volatile("s_waitcnt lgkmcnt(0)" ::: "memory");
        if (lane == 0) fV[w] = it + 1;   // wave w in {0..6}
      }
    }

    // dual terms -> dslot (dead since epilogue), then wave-0 reduction
    if (uRole && q4 == 0)
      dslot[g4] = (g4 < n0) ? inv_n0 * (rv[g4] - __logf(Sfin)) : 0.f;
    if (vRole && q4 == 0)
      dslot[48 + g4] = (g4 < n1) ? inv_n1 * (cv[g4] - __logf(Tfin)) : 0.f;
    __syncthreads();                    // wave 7 (skipped D) re-joins here
    if (t < 64) {
      float val = dslot[t] + dslot[64 + t];
      if (t < 32) val += dslot[128 + t];
      #pragma unroll
      for (int d = 1; d < 64; d <<= 1) val += __shfl_xor(val, d);

      float f320 = EPS * val
                 - 0.5f * (EPS * __logf((float)n0) + EPS * __logf((float)n1) + 0.002f);
      if (t == 0) dcross[b] = f320;
      unsigned old = 0;
      if (t == 0) { __threadfence(); old = atomicAdd(&ticket[b], 1u); }
      old = __shfl(old, 0);
      if (old == 1) {        // second arriver finishes batch b
        __threadfence();
        finish_batch(b, t, fused, dcross, lnw, lnb, Wcls, bcls, out);
      }
    }
  } else {
    // ================= rep / MLP path =================
    const int b = bid - 64;
    float* repv = (float*)smem;               // [1536]
    float* afl  = (float*)(smem + 8192);      // [128]
    float* bfl  = (float*)(smem + 8704);      // [128]
    float* red  = (float*)(smem + 9216);      // scratch

    if (t < 128) {
      int a_ = amask[b*128 + t], tt_ = ttid[b*128 + t];
      afl[t] = (a_ == 1 && tt_ == 0) ? 1.0f : 0.0f;
      bfl[t] = (a_ == 1 && tt_ == 1) ? 1.0f : 0.0f;
    }
    __syncthreads();
    if (t < 64) {
      float s = afl[t] + afl[t + 64];
      #pragma unroll
      for (int d = 32; d > 0; d >>= 1) s += __shfl_down(s, d);
      if (t == 0) red[0] = s;
    } else if (t < 128) {
      int l = t - 64;
      float s = bfl[l] + bfl[l + 64];
      #pragma unroll
      for (int d = 32; d > 0; d >>= 1) s += __shfl_down(s, d);
      if (l == 0) red[1] = s;
    }
    __syncthreads();
    const float n0 = fmaxf(red[0], 1.0f), n1 = fmaxf(red[1], 1.0f);

    const float* Hb = H + (size_t)b * (128 * 768);
    if (t < 384) {   // mean pool: float2 columns, deep unroll for ILP
      const float* cp = Hb + 2 * t;
      float s0x = 0.f, s0y = 0.f, s1x = 0.f, s1y = 0.f;
      #pragma unroll 16
      for (int i = 0; i < 128; i++) {
        float2 h = *(const float2*)(cp + i * 768);
        float av = afl[i], bv = bfl[i];
        s0x += av * h.x; s0y += av * h.y;
        s1x += bv * h.x; s1y += bv * h.y;
      }
      repv[768 + 2*t]     = s0x / n0 - s1x / n1;
      repv[768 + 2*t + 1] = s0y / n0 - s1y / n1;
      float2 h0 = *(const float2*)(cp);   // row 0 = cls
      repv[2*t] = h0.x; repv[2*t + 1] = h0.y;
    }
    __syncthreads();

    const int klane = t & 63, og = t >> 6;
    float4 rr[6];
    #pragma unroll
    for (int c4 = 0; c4 < 6; c4++)
      rr[c4] = *(const float4*)(repv + c4 * 256 + klane * 4);
    const float gg = 1.0f / (1.0f + __expf(-gate[0]));
    #pragma unroll 2
    for (int oo = og; oo < 320; oo += 16) {   // dual-row matvec
      const int o1 = oo + 8;
      const float* w0p = (oo < 256) ? (Wc + (size_t)oo * 1536)
                                    : (Ws + (size_t)(oo - 256) * 1536);
      const float* w1p = (o1 < 256) ? (Wc + (size_t)o1 * 1536)
                                    : (Ws + (size_t)(o1 - 256) * 1536);
      float sa = 0.f, sb = 0.f;
      #pragma unroll
      for (int c4 = 0; c4 < 6; c4++) {
        float4 wa = *(const float4*)(w0p + c4 * 256 + klane * 4);
        float4 wb = *(const float4*)(w1p + c4 * 256 + klane * 4);
        sa += rr[c4].x * wa.x + rr[c4].y * wa.y + rr[c4].z * wa.z + rr[c4].w * wa.w;
        sb += rr[c4].x * wb.x + rr[c4].y * wb.y + rr[c4].z * wb.z + rr[c4].w * wb.w;
      }
      #pragma unroll
      for (int d = 32; d > 0; d >>= 1) { sa += __shfl_down(sa, d); sb += __shfl_down(sb, d); }
      if (klane == 0) {
        float ba = (oo < 256) ? bc[oo] : bs[oo - 256];
        float bb = (o1 < 256) ? bc[o1] : bs[o1 - 256];
        fused[b * 320 + oo] = (sa + ba) * ((oo < 256) ? (1.0f - gg) : gg);
        fused[b * 320 + o1] = (sb + bb) * ((o1 < 256) ? (1.0f - gg) : gg);
      }
    }

    __syncthreads();                 // all fused stores drained
    if (t < 64) {
      unsigned old = 0;
      if (t == 0) { __threadfence(); old = atomicAdd(&ticket[b], 1u); }
      old = __shfl(old, 0);
      if (old == 1) {                // second arriver finishes batch b
        __threadfence();
        finish_batch(b, t, fused, dcross, lnw, lnb, Wcls, bcls, out);
      }
    }
  }
}

extern "C" void kernel_launch(void* const* d_in, const int* in_sizes, int n_in,
                              void* d_out, int out_size, void* d_ws, size_t ws_size,
                              hipStream_t stream)
{
  (void)in_sizes; (void)n_in; (void)out_size; (void)ws_size;
  const float* H    = (const float*)d_in[0];
  const int*   tt   = (const int*)d_in[1];
  const int*   am   = (const int*)d_in[2];
  const float* Wc   = (const float*)d_in[3];
  const float* bc   = (const float*)d_in[4];
  const float* Ws   = (const float*)d_in[5];
  const float* bs   = (const float*)d_in[6];
  const float* gate = (const float*)d_in[7];
  const float* lnw  = (const float*)d_in[8];
  const float* lnb  = (const float*)d_in[9];
  const float* Wcls = (const float*)d_in[10];
  const float* bcls = (const float*)d_in[11];
  float* out = (float*)d_out;

  float* dcross = (float*)d_ws;                        // 64
  float* fusedv = dcross + 64;                         // 64*320
  unsigned* ticket = (unsigned*)(fusedv + 64 * 320);   // 64 (zeroed per launch)

  hipMemsetAsync(ticket, 0, 64 * sizeof(unsigned), stream);
  k_mega<<<dim3(128), dim3(512), 0, stream>>>(H, tt, am, Wc, bc, Ws, bs, gate,
                                              lnw, lnb, Wcls, bcls,
                                              dcross, fusedv, ticket, out);
}

// Round 11
// 125.210 us; speedup vs baseline: 1.0497x; 1.0497x over previous
//
#include <hip/hip_runtime.h>
#include <hip/hip_fp16.h>
#include <math.h>

#define EPS 0.05f
#define INV_EPS 20.0f
#define BIGF 1e30f

typedef short bf16x8 __attribute__((ext_vector_type(8)));
typedef float f32x4 __attribute__((ext_vector_type(4)));

// HW packed f32->bf16 (RNE), lo16 = bf16(a), hi16 = bf16(b)
__device__ __forceinline__ unsigned cvtpk(float a, float b) {
  unsigned r;
  asm("v_cvt_pk_bf16_f32 %0, %1, %2" : "=v"(r) : "v"(a), "v"(b));
  return r;
}
// barrier that drains LDS ops only -- global prefetch stays in flight
__device__ __forceinline__ void barrier_lg() {
  asm volatile("s_waitcnt lgkmcnt(0)" ::: "memory");
  __builtin_amdgcn_s_barrier();
  asm volatile("" ::: "memory");
}

struct Q4 { float4 a, b, c, d; };
__device__ __forceinline__ void loadQ(Q4& q, const float* p) {
  q.a = *(const float4*)p;       q.b = *(const float4*)(p + 4);
  q.c = *(const float4*)(p + 8); q.d = *(const float4*)(p + 12);
}
// pack 16 f32 -> bf16 (HW cvt_pk), store 32B to LDS, accumulate bf16-rounded |x|^2
__device__ __forceinline__ void packQ(short* dst, const Q4& q, float& sq) {
  uint4 w0, w1;
  w0.x = cvtpk(q.a.x, q.a.y); w0.y = cvtpk(q.a.z, q.a.w);
  w0.z = cvtpk(q.b.x, q.b.y); w0.w = cvtpk(q.b.z, q.b.w);
  w1.x = cvtpk(q.c.x, q.c.y); w1.y = cvtpk(q.c.z, q.c.w);
  w1.z = cvtpk(q.d.x, q.d.y); w1.w = cvtpk(q.d.z, q.d.w);
  unsigned ws[8] = {w0.x, w0.y, w0.z, w0.w, w1.x, w1.y, w1.z, w1.w};
  #pragma unroll
  for (int k = 0; k < 8; k++) {
    float lo = __uint_as_float(ws[k] << 16);
    float hi = __uint_as_float(ws[k] & 0xffff0000u);
    sq += lo * lo + hi * hi;
  }
  *(uint4*)dst = w0;
  *(uint4*)(dst + 8) = w1;
}

// ---- LDS arena (bytes), phase-lifetime aliased:
#define S_HSA   0        // short[128][72] = 18432
#define S_HSB   18432    //               -> 36864
#define S_KR    36864    // float[48][116] = 22272 -> 59136
#define S_DIAG  59136    // f32[128]  -> 59648 (per H-row bf16 |h|^2)
#define S_DSL   59648    // f32[160]  -> 60288 (compact diag; later dual terms)
#define S_IA    60288    // int[48]   -> 60480
#define S_IB    60480    // int[112]  -> 60928
#define S_RV    60928    // f32[48]   -> 61120
#define S_CV    61120    // f32[112]  -> 61568
#define S_CNT   61568    // int[4]    -> 61584
#define S_UV    61584    // f32[48]   -> 61776
#define S_VV    61776    // f32[112]  -> 62224
#define SMEM_SZ 62240

// single-batch LayerNorm + classifier, one wave (64 lanes)
__device__ __forceinline__ void finish_batch(int b, int lane,
    const float* __restrict__ fusedv, const float* __restrict__ dxv,
    const float* __restrict__ lnw, const float* __restrict__ lnb,
    const float* __restrict__ Wcls, const float* __restrict__ bcls,
    float* __restrict__ out)
{
  float f320 = __hip_atomic_load(dxv + b, __ATOMIC_RELAXED, __HIP_MEMORY_SCOPE_AGENT);
  float fv[5];
  #pragma unroll
  for (int c = 0; c < 5; c++)
    fv[c] = __hip_atomic_load(fusedv + b * 320 + c * 64 + lane,
                              __ATOMIC_RELAXED, __HIP_MEMORY_SCOPE_AGENT);
  float s = ((fv[0] + fv[1]) + (fv[2] + fv[3])) + fv[4];
  if (lane == 0) s += f320;
  #pragma unroll
  for (int d = 1; d < 64; d <<= 1) s += __shfl_xor(s, d);
  const float mu = s * (1.0f / 321.0f);
  float v = 0.f;
  #pragma unroll
  for (int c = 0; c < 5; c++) { float dd = fv[c] - mu; v += dd * dd; }
  if (lane == 0) { float dd = f320 - mu; v += dd * dd; }
  #pragma unroll
  for (int d = 1; d < 64; d <<= 1) v += __shfl_xor(v, d);
  const float rstd = rsqrtf(v * (1.0f / 321.0f) + 1e-5f);
  float p0 = 0.f, p1 = 0.f;
  #pragma unroll
  for (int c = 0; c < 5; c++) {
    int i = c * 64 + lane;
    float h = (fv[c] - mu) * rstd * lnw[i] + lnb[i];
    p0 += h * Wcls[i];
    p1 += h * Wcls[321 + i];
  }
  if (lane == 0) {
    float h = (f320 - mu) * rstd * lnw[320] + lnb[320];
    p0 += h * Wcls[320];
    p1 += h * Wcls[641];
  }
  #pragma unroll
  for (int d = 1; d < 64; d <<= 1) { p0 += __shfl_xor(p0, d); p1 += __shfl_xor(p1, d); }
  if (lane == 0) {
    out[b * 2]     = p0 + bcls[0];
    out[b * 2 + 1] = p1 + bcls[1];
  }
}

__global__ __launch_bounds__(512)
void k_mega(const float* __restrict__ H, const int* __restrict__ ttid,
            const int* __restrict__ amask,
            const float* __restrict__ Wc, const float* __restrict__ bc,
            const float* __restrict__ Ws, const float* __restrict__ bs,
            const float* __restrict__ gate,
            const float* __restrict__ lnw, const float* __restrict__ lnb,
            const float* __restrict__ Wcls, const float* __restrict__ bcls,
            float* __restrict__ dcross, float* __restrict__ fused,
            unsigned* __restrict__ ticket, float* __restrict__ out)
{
  __shared__ __align__(16) char smem[SMEM_SZ];
  const int t = threadIdx.x;
  const int bid = blockIdx.x;

  if (bid < 64) {
    // ================= compact-support Sinkhorn =================
    const int b = bid;
    short*  HsA  = (short*)(smem + S_HSA);
    short*  HsB  = (short*)(smem + S_HSB);
    float*  Kr   = (float*)(smem + S_KR);
    float*  diag = (float*)(smem + S_DIAG);
    float*  dslot= (float*)(smem + S_DSL);
    int*    ia   = (int*)(smem + S_IA);
    int*    ib   = (int*)(smem + S_IB);
    float*  rv   = (float*)(smem + S_RV);
    float*  cv   = (float*)(smem + S_CV);
    int*    cnts = (int*)(smem + S_CNT);
    float*  uv   = (float*)(smem + S_UV);
    float*  vv   = (float*)(smem + S_VV);

    const int lane = t & 63;
    const int w = t >> 6;

    // ---- issue 4 H chunks FIRST (independent of masks; 4-deep pipeline) ----
    const float* Hb = H + (size_t)b * (128 * 768);
    const int srow = t >> 2, sc0 = (t & 3) * 16;
    const float* srcB = Hb + srow * 768 + sc0;
    Q4 q0, q1, q2, q3;
    loadQ(q0, srcB);
    loadQ(q1, srcB + 64);
    loadQ(q2, srcB + 128);
    loadQ(q3, srcB + 192);

    // ---- Phase A: compact index lists via ballot prefix-sum ----
    int flagA = 0, flagB = 0;
    unsigned long long mA = 0, mB = 0;
    if (t < 128) {
      int a_ = amask[b*128 + t], tt_ = ttid[b*128 + t];
      flagA = (a_ == 1 && tt_ == 0);
      flagB = (a_ == 1 && tt_ == 1);
      mA = __ballot(flagA);
      mB = __ballot(flagB);
      if (lane == 0) { cnts[w] = __popcll(mA); cnts[2 + w] = __popcll(mB); }
    }
    for (int e = t; e < 48 * 116; e += 512) Kr[e] = BIGF;   // prefill
    __syncthreads();
    const int n0 = cnts[0] + cnts[1];   // <= 47
    const int n1 = cnts[2] + cnts[3];   // <= 112
    if (t < 128) {
      int offA = (w == 1) ? cnts[0] : 0;
      int offB = (w == 1) ? cnts[2] : 0;
      unsigned long long below = (1ull << lane) - 1ull;
      if (flagA) ia[offA + __popcll(mA & below)] = t;
      if (flagB) ib[offB + __popcll(mB & below)] = t;
    }
    float sq = 0.f;
    packQ(HsA + srow * 72 + sc0, q0, sq);   // chunk 0 -> HsA
    __syncthreads();    // ia/ib + HsA chunk0 visible

    // ---- Phase B: linear staging of all 128 rows; compact MFMA via
    //      per-lane fragment row indices read once through ia/ib ----
    const int wv = t >> 6;
    const int fm = lane & 15, fg = lane >> 4;
    int ar0 = 0, ar1 = 0, ar2 = 0, br = 0;
    if (wv < 7) {
      ar0 = (fm      < n0) ? ia[fm]      : 0;
      ar1 = (16 + fm < n0) ? ia[16 + fm] : 0;
      ar2 = (32 + fm < n0) ? ia[32 + fm] : 0;
      br  = (wv * 16 + fm < n1) ? ib[wv * 16 + fm] : 0;
    }

    f32x4 acc[3];
    #pragma unroll
    for (int r = 0; r < 3; r++) { acc[r][0]=0.f; acc[r][1]=0.f; acc[r][2]=0.f; acc[r][3]=0.f; }

    #pragma unroll
    for (int kc = 0; kc < 12; kc++) {
      if (kc) barrier_lg();      // chunk kc visible; global prefetch NOT drained
      short* cur = (kc & 1) ? HsB : HsA;
      short* nxt = (kc & 1) ? HsA : HsB;
      if (kc < 8) {              // prefetch chunk kc+4 into the just-freed slot
        const float* s2 = srcB + (kc + 4) * 64;
        if ((kc & 3) == 0)      loadQ(q0, s2);
        else if ((kc & 3) == 1) loadQ(q1, s2);
        else if ((kc & 3) == 2) loadQ(q2, s2);
        else                    loadQ(q3, s2);
      }
      if (kc < 11) {             // pack+store chunk kc+1 into the other buffer
        short* d = nxt + srow * 72 + sc0;
        const int m = (kc + 1) & 3;
        if (m == 0)      packQ(d, q0, sq);
        else if (m == 1) packQ(d, q1, sq);
        else if (m == 2) packQ(d, q2, sq);
        else             packQ(d, q3, sq);
      }
      if (wv < 7) {              // 3 row-tiles x col-tile wv, 21 tiles total
        #pragma unroll
        for (int ks = 0; ks < 2; ks++) {
          bf16x8 bfr = *(const bf16x8*)(cur + br * 72 + ks * 32 + fg * 8);
          bf16x8 a0f = *(const bf16x8*)(cur + ar0 * 72 + ks * 32 + fg * 8);
          acc[0] = __builtin_amdgcn_mfma_f32_16x16x32_bf16(a0f, bfr, acc[0], 0, 0, 0);
          bf16x8 a1f = *(const bf16x8*)(cur + ar1 * 72 + ks * 32 + fg * 8);
          acc[1] = __builtin_amdgcn_mfma_f32_16x16x32_bf16(a1f, bfr, acc[1], 0, 0, 0);
          bf16x8 a2f = *(const bf16x8*)(cur + ar2 * 72 + ks * 32 + fg * 8);
          acc[2] = __builtin_amdgcn_mfma_f32_16x16x32_bf16(a2f, bfr, acc[2], 0, 0, 0);
        }
      }
    }
    // per-row bf16 square-sum -> diag
    {
      float s = sq;
      s += __shfl_xor(s, 1); s += __shfl_xor(s, 2);
      if ((t & 3) == 0) diag[srow] = s;
    }
    __syncthreads();
    if (t < 160)   // compact diag gather
      dslot[t] = diag[(t < 48) ? ((t < n0) ? ia[t] : 0)
                               : ((t - 48 < n1) ? ib[t - 48] : 0)];
    __syncthreads();

    // ---- epilogue: Ce = sqrt(dA+dB-2G)*INV_EPS straight from f32 acc ----
    if (wv < 7) {
      int j = wv * 16 + fm;
      if (j < n1) {
        float dj = dslot[48 + j];
        #pragma unroll
        for (int r = 0; r < 3; r++) {
          #pragma unroll
          for (int q = 0; q < 4; q++) {
            int i = r * 16 + fg * 4 + q;
            if (i < n0) {
              float d2 = fmaxf(dslot[i] + dj - 2.0f * acc[r][q], 1e-6f);
              Kr[i * 116 + j] = sqrtf(d2) * INV_EPS;
            }
          }
        }
      }
    }
    __syncthreads();

    // ---- Phase C: shifts r/c, K transform in place ----
    if (t < 192) {  // r_i = min_j Ce
      int r = t >> 2, c = t & 3;
      const float* row = Kr + r * 116 + c * 28;
      float mn = BIGF;
      #pragma unroll
      for (int g = 0; g < 7; g++) {
        float4 x = *(const float4*)(row + g * 4);
        mn = fminf(mn, fminf(fminf(x.x, x.y), fminf(x.z, x.w)));
      }
      mn = fminf(mn, __shfl_xor(mn, 1));
      mn = fminf(mn, __shfl_xor(mn, 2));
      if (c == 0) rv[r] = mn;
    }
    __syncthreads();
    if (t < 448) {  // c_j = min_{i<n0} (Ce - r_i)
      int cl = t >> 2, rr = t & 3;
      float mn = BIGF;
      #pragma unroll
      for (int g = 0; g < 12; g++) {
        int i = rr * 12 + g;
        float v = (i < n0) ? (Kr[i * 116 + cl] - rv[i]) : BIGF;
        mn = fminf(mn, v);
      }
      mn = fminf(mn, __shfl_xor(mn, 1));
      mn = fminf(mn, __shfl_xor(mn, 2));
      if (rr == 0) cv[cl] = mn;
    }
    __syncthreads();
    for (int i = t >> 7; i < 48; i += 4) {  // K = exp(min(r+c-Ce,0))
      float ri = rv[i];
      for (int j = t & 127; j < 112; j += 128) {
        float ce = Kr[i * 116 + j];
        Kr[i * 116 + j] = __expf(fminf(ri + cv[j] - ce, 0.f));
      }
    }
    const float inv_n0 = 1.0f / (float)n0;
    const float inv_n1 = 1.0f / (float)n1;
    if (t < 112) vv[t] = (t < n1) ? inv_n1 * __expf(-cv[t]) : 0.f;  // v init
    __syncthreads();

    // ---- Phase D: 8-wave cooperative scaling iterations (r9 structure) ----
    // u-step: t<192 -> (row g4 = t>>2, slice q4 = t&3), 28-elem row slices
    // v-step: t<448 -> (col g4, slice q4), 12-elem column slices
    const int g4 = t >> 2, q4 = t & 3;
    const bool uRole = (t < 192);
    const bool vRole = (t < 448);

    float ku[28];
    if (uRole) {
      const float* kp = Kr + g4 * 116 + 28 * q4;
      #pragma unroll
      for (int i = 0; i < 7; i++) {
        float4 x = *(const float4*)(kp + 4 * i);
        ku[4*i] = x.x; ku[4*i+1] = x.y; ku[4*i+2] = x.z; ku[4*i+3] = x.w;
      }
    }
    float kv[12];
    if (vRole) {
      #pragma unroll
      for (int i = 0; i < 12; i++) kv[i] = Kr[(12 * q4 + i) * 116 + g4];
    }
    const float a_r = (uRole && g4 < n0) ? inv_n0 : 0.f;
    const float b_j = (vRole && g4 < n1) ? inv_n1 : 0.f;
    float Sfin = 1.f, Tfin = 1.f;

    for (int it = 0; it < 30; it++) {
      if (uRole) {                       // S_r = sum_j K[r][j] v_j
        const float* vp = vv + 28 * q4;
        float a0 = 0.f, a1 = 0.f, a2 = 0.f, a3 = 0.f;
        #pragma unroll
        for (int i = 0; i < 7; i++) {
          float4 v4 = *(const float4*)(vp + 4 * i);
          a0 += ku[4*i]   * v4.x; a1 += ku[4*i+1] * v4.y;
          a2 += ku[4*i+2] * v4.z; a3 += ku[4*i+3] * v4.w;
        }
        float s = (a0 + a1) + (a2 + a3);
        s += __shfl_xor(s, 1);
        s += __shfl_xor(s, 2);
        Sfin = s;
        if (q4 == 0) uv[g4] = a_r * __builtin_amdgcn_rcpf(s);
      }
      __syncthreads();
      if (vRole) {                       // T_j = sum_i K[i][j] u_i
        const float* up = uv + 12 * q4;
        float4 u0 = *(const float4*)(up);
        float4 u1 = *(const float4*)(up + 4);
        float4 u2 = *(const float4*)(up + 8);
        float p0 = kv[0]*u0.x + kv[1]*u0.y + kv[2]*u0.z + kv[3]*u0.w;
        float p1 = kv[4]*u1.x + kv[5]*u1.y + kv[6]*u1.z + kv[7]*u1.w;
        float p2 = kv[8]*u2.x + kv[9]*u2.y + kv[10]*u2.z + kv[11]*u2.w;
        float tsum = p0 + p1 + p2;
        tsum += __shfl_xor(tsum, 1);
        tsum += __shfl_xor(tsum, 2);
        Tfin = tsum;
        if (q4 == 0) vv[g4] = b_j * __builtin_amdgcn_rcpf(tsum);
      }
      __syncthreads();
    }

    // dual terms -> dslot (dead since epilogue), then wave-0 reduction
    if (uRole && q4 == 0)
      dslot[g4] = (g4 < n0) ? inv_n0 * (rv[g4] - __logf(Sfin)) : 0.f;
    if (vRole && q4 == 0)
      dslot[48 + g4] = (g4 < n1) ? inv_n1 * (cv[g4] - __logf(Tfin)) : 0.f;
    __syncthreads();
    if (t < 64) {
      float val = dslot[t] + dslot[64 + t];
      if (t < 32) val += dslot[128 + t];
      #pragma unroll
      for (int d = 1; d < 64; d <<= 1) val += __shfl_xor(val, d);

      float f320 = EPS * val
                 - 0.5f * (EPS * __logf((float)n0) + EPS * __logf((float)n1) + 0.002f);
      if (t == 0) dcross[b] = f320;
      unsigned old = 0;
      if (t == 0) { __threadfence(); old = atomicAdd(&ticket[b], 1u); }
      old = __shfl(old, 0);
      if (old == 1) {        // second arriver finishes batch b
        __threadfence();
        finish_batch(b, t, fused, dcross, lnw, lnb, Wcls, bcls, out);
      }
    }
  } else {
    // ================= rep / MLP path =================
    const int b = bid - 64;
    float* repv = (float*)smem;               // [1536]
    float* afl  = (float*)(smem + 8192);      // [128]
    float* bfl  = (float*)(smem + 8704);      // [128]
    float* red  = (float*)(smem + 9216);      // scratch

    if (t < 128) {
      int a_ = amask[b*128 + t], tt_ = ttid[b*128 + t];
      afl[t] = (a_ == 1 && tt_ == 0) ? 1.0f : 0.0f;
      bfl[t] = (a_ == 1 && tt_ == 1) ? 1.0f : 0.0f;
    }
    __syncthreads();
    if (t < 64) {
      float s = afl[t] + afl[t + 64];
      #pragma unroll
      for (int d = 32; d > 0; d >>= 1) s += __shfl_down(s, d);
      if (t == 0) red[0] = s;
    } else if (t < 128) {
      int l = t - 64;
      float s = bfl[l] + bfl[l + 64];
      #pragma unroll
      for (int d = 32; d > 0; d >>= 1) s += __shfl_down(s, d);
      if (l == 0) red[1] = s;
    }
    __syncthreads();
    const float n0 = fmaxf(red[0], 1.0f), n1 = fmaxf(red[1], 1.0f);

    const float* Hb = H + (size_t)b * (128 * 768);
    if (t < 384) {   // mean pool: float2 columns, deep unroll for ILP
      const float* cp = Hb + 2 * t;
      float s0x = 0.f, s0y = 0.f, s1x = 0.f, s1y = 0.f;
      #pragma unroll 16
      for (int i = 0; i < 128; i++) {
        float2 h = *(const float2*)(cp + i * 768);
        float av = afl[i], bv = bfl[i];
        s0x += av * h.x; s0y += av * h.y;
        s1x += bv * h.x; s1y += bv * h.y;
      }
      repv[768 + 2*t]     = s0x / n0 - s1x / n1;
      repv[768 + 2*t + 1] = s0y / n0 - s1y / n1;
      float2 h0 = *(const float2*)(cp);   // row 0 = cls
      repv[2*t] = h0.x; repv[2*t + 1] = h0.y;
    }
    __syncthreads();

    const int klane = t & 63, og = t >> 6;
    float4 rr[6];
    #pragma unroll
    for (int c4 = 0; c4 < 6; c4++)
      rr[c4] = *(const float4*)(repv + c4 * 256 + klane * 4);
    const float gg = 1.0f / (1.0f + __expf(-gate[0]));
    #pragma unroll 2
    for (int oo = og; oo < 320; oo += 16) {   // dual-row matvec
      const int o1 = oo + 8;
      const float* w0p = (oo < 256) ? (Wc + (size_t)oo * 1536)
                                    : (Ws + (size_t)(oo - 256) * 1536);
      const float* w1p = (o1 < 256) ? (Wc + (size_t)o1 * 1536)
                                    : (Ws + (size_t)(o1 - 256) * 1536);
      float sa = 0.f, sb = 0.f;
      #pragma unroll
      for (int c4 = 0; c4 < 6; c4++) {
        float4 wa = *(const float4*)(w0p + c4 * 256 + klane * 4);
        float4 wb = *(const float4*)(w1p + c4 * 256 + klane * 4);
        sa += rr[c4].x * wa.x + rr[c4].y * wa.y + rr[c4].z * wa.z + rr[c4].w * wa.w;
        sb += rr[c4].x * wb.x + rr[c4].y * wb.y + rr[c4].z * wb.z + rr[c4].w * wb.w;
      }
      #pragma unroll
      for (int d = 32; d > 0; d >>= 1) { sa += __shfl_down(sa, d); sb += __shfl_down(sb, d); }
      if (klane == 0) {
        float ba = (oo < 256) ? bc[oo] : bs[oo - 256];
        float bb = (o1 < 256) ? bc[o1] : bs[o1 - 256];
        fused[b * 320 + oo] = (sa + ba) * ((oo < 256) ? (1.0f - gg) : gg);
        fused[b * 320 + o1] = (sb + bb) * ((o1 < 256) ? (1.0f - gg) : gg);
      }
    }

    __syncthreads();                 // all fused stores drained
    if (t < 64) {
      unsigned old = 0;
      if (t == 0) { __threadfence(); old = atomicAdd(&ticket[b], 1u); }
      old = __shfl(old, 0);
      if (old == 1) {                // second arriver finishes batch b
        __threadfence();
        finish_batch(b, t, fused, dcross, lnw, lnb, Wcls, bcls, out);
      }
    }
  }
}

extern "C" void kernel_launch(void* const* d_in, const int* in_sizes, int n_in,
                              void* d_out, int out_size, void* d_ws, size_t ws_size,
                              hipStream_t stream)
{
  (void)in_sizes; (void)n_in; (void)out_size; (void)ws_size;
  const float* H    = (const float*)d_in[0];
  const int*   tt   = (const int*)d_in[1];
  const int*   am   = (const int*)d_in[2];
  const float* Wc   = (const float*)d_in[3];
  const float* bc   = (const float*)d_in[4];
  const float* Ws   = (const float*)d_in[5];
  const float* bs   = (const float*)d_in[6];
  const float* gate = (const float*)d_in[7];
  const float* lnw  = (const float*)d_in[8];
  const float* lnb  = (const float*)d_in[9];
  const float* Wcls = (const float*)d_in[10];
  const float* bcls = (const float*)d_in[11];
  float* out = (float*)d_out;

  float* dcross = (float*)d_ws;                        // 64
  float* fusedv = dcross + 64;                         // 64*320
  unsigned* ticket = (unsigned*)(fusedv + 64 * 320);   // 64 (zeroed per launch)

  hipMemsetAsync(ticket, 0, 64 * sizeof(unsigned), stream);
  k_mega<<<dim3(128), dim3(512), 0, stream>>>(H, tt, am, Wc, bc, Ws, bs, gate,
                                              lnw, lnb, Wcls, bcls,
                                              dcross, fusedv, ticket, out);
}